// Round 1
// baseline (70.552 us; speedup 1.0000x reference)
//
#include <hip/hip_runtime.h>

// ConvDeepSet: B=16, N=512, M=1024, CIN=7 (C=8 with ones-channel), COUT=64.
// out[b,m,o] = sum_c f(b,m,c) * W[o,c] + bias[o]
//   f[...,0]   = density  = sum_n exp(k_0 * d)
//   f[...,c>0] = (sum_n ctx[n,c] * exp(k_c * d)) / (density + 1e-8)
//   d = (context_in[b,n] - target_in[b,m])^2 ; k_c = -0.5 * exp(-2*sigma_c)
//
// Uniform-sigma fast path (always taken on the bench data) linearizes the
// exponent:  k*(ci-ti)^2 = A_n + B_n*ti + Q,  A_n=k*ci^2, B_n=-2k*ci, Q=k*ti^2.
// Q is constant over the n-loop, so 2^Q is factored out of the whole sum and
// applied once per thread after accumulation (exact rescale, same epsilon
// semantics since the density division happens after rescale).
// Accumulation uses packed v_pk_fma_f32 (dual-issue fp32) via inline asm.
//
// LDS record per n (48 B, 16B-aligned sub-reads):
//   uniform:  [A, B, 1, x1 | x2, x3, x4, x5 | x6, x7, pad, pad]
//   fallback: [ci, 0, 1, x1 | x2, x3, x4, x5 | x6, x7, pad, pad]

namespace {
constexpr int Bc    = 16;
constexpr int Nc    = 512;
constexpr int Mc    = 1024;
constexpr int CINc  = 7;
constexpr int Cc    = 8;      // 1 + CIN
constexpr int CP    = 9;      // padded channel stride for the reduce buffer
constexpr int COUTc = 64;
constexpr int TM    = 32;     // m-values per block
constexpr int NCH   = 16;     // n-chunks per block
constexpr int NPC   = Nc / NCH;       // 32 n per chunk
constexpr int THREADS = TM * NCH;     // 512 threads, 8 waves/block
constexpr int REC   = 12;             // floats per LDS context record (48 B)
constexpr float LOG2E = 1.4426950408889634f;
typedef float f32x2 __attribute__((ext_vector_type(2)));
}

__global__ __launch_bounds__(THREADS) void convdeepset_kernel(
    const float* __restrict__ context_in,   // (B,N,1)
    const float* __restrict__ context_out,  // (B,N,CIN)
    const float* __restrict__ target_in,    // (B,M,1)
    const float* __restrict__ sigma,        // (C,)
    const float* __restrict__ W,            // (COUT,C)
    const float* __restrict__ bias,         // (COUT,)
    float* __restrict__ out)                // (B,M,COUT)
{
    __shared__ float s_ctx[Nc * REC];          // 24 KiB context records
    __shared__ float s_red[NCH][TM][CP];       // partial sums (padded stride 9)
    __shared__ float s_tot[TM][Cc];
    __shared__ float s_f[TM][Cc];
    __shared__ float s_Wt[Cc][COUTc];
    __shared__ float s_bias[COUTc];

    const int t   = threadIdx.x;
    const int blk = blockIdx.x;
    const int b   = blk / (Mc / TM);
    const int m0  = (blk % (Mc / TM)) * TM;

    // ---- per-thread k2 from sigma (wave-uniform scalar loads, no LDS) ----
    float k2[Cc];
    #pragma unroll
    for (int c = 0; c < Cc; c++) {
        const float s = sigma[c];
        k2[c] = -0.5f * __builtin_amdgcn_exp2f(-2.0f * s * LOG2E) * LOG2E;
    }
    bool uniform = true;
    #pragma unroll
    for (int c = 1; c < Cc; c++) uniform = uniform && (k2[c] == k2[0]);

    // ---- stage constants ----
    if (t < COUTc) s_bias[t] = bias[t];
    if (t < COUTc * Cc) {               // 512 threads == 512 elements of W
        const int o = t / Cc, c = t % Cc;
        s_Wt[c][o] = W[t];
    }
    // ---- stage per-batch context records ----
    {
        const int n = t;                // THREADS == Nc
        const float ci = context_in[b * Nc + n];
        if (uniform) {
            s_ctx[n * REC + 0] = (k2[0] * ci) * ci;   // A_n
            s_ctx[n * REC + 1] = -2.0f * k2[0] * ci;  // B_n
        } else {
            s_ctx[n * REC + 0] = ci;
            s_ctx[n * REC + 1] = 0.0f;
        }
        s_ctx[n * REC + 2] = 1.0f;                    // ones channel
    }
    #pragma unroll
    for (int r = 0; r < (Nc * CINc) / THREADS; r++) {   // 7 iters, exact
        const int e = r * THREADS + t;
        const int n = e / CINc, c = e % CINc;
        s_ctx[n * REC + 3 + c] = context_out[b * Nc * CINc + e];
    }
    __syncthreads();

    const int mi  = t % TM;   // m within tile
    const int ncq = t / TM;   // n-chunk
    const float ti = target_in[b * Mc + m0 + mi];
    const int nbase = ncq * NPC;

    f32x2 a01 = {0.0f, 0.0f}, a23 = {0.0f, 0.0f};
    f32x2 a45 = {0.0f, 0.0f}, a67 = {0.0f, 0.0f};
    float scale;

    if (uniform) {
        // 1 fma + 1 exp2 + 4 packed fma per (m,n) pair; LDS reads are
        // wave-broadcast (2 distinct addrs/wave -> conflict-free).
        #pragma unroll 8
        for (int j = 0; j < NPC; j++) {
            const float* rec = &s_ctx[(nbase + j) * REC];
            const float4 c0 = *(const float4*)rec;        // A, B, 1, x1
            const float4 c1 = *(const float4*)(rec + 4);  // x2..x5
            const f32x2  c2 = *(const f32x2*)(rec + 8);   // x6, x7
            const float w = __builtin_amdgcn_exp2f(fmaf(c0.y, ti, c0.x));
            f32x2 wv = {w, w};
            f32x2 p0 = {c0.z, c0.w};
            f32x2 p1 = {c1.x, c1.y};
            f32x2 p2 = {c1.z, c1.w};
            asm("v_pk_fma_f32 %0, %1, %2, %0" : "+v"(a01) : "v"(p0), "v"(wv));
            asm("v_pk_fma_f32 %0, %1, %2, %0" : "+v"(a23) : "v"(p1), "v"(wv));
            asm("v_pk_fma_f32 %0, %1, %2, %0" : "+v"(a45) : "v"(p2), "v"(wv));
            asm("v_pk_fma_f32 %0, %1, %2, %0" : "+v"(a67) : "v"(c2), "v"(wv));
        }
        scale = __builtin_amdgcn_exp2f((k2[0] * ti) * ti);   // 2^{k2*ti^2}
    } else {
        // Generic per-channel path (not taken on bench data).
        #pragma unroll 4
        for (int j = 0; j < NPC; j++) {
            const float* rec = &s_ctx[(nbase + j) * REC];
            const float4 c0 = *(const float4*)rec;        // ci, 0, 1, x1
            const float4 c1 = *(const float4*)(rec + 4);  // x2..x5
            const f32x2  c2 = *(const f32x2*)(rec + 8);   // x6, x7
            const float diff = c0.x - ti;
            const float d = diff * diff;
            a01.x += __builtin_amdgcn_exp2f(k2[0] * d);
            a01.y += c0.w * __builtin_amdgcn_exp2f(k2[1] * d);
            a23.x += c1.x * __builtin_amdgcn_exp2f(k2[2] * d);
            a23.y += c1.y * __builtin_amdgcn_exp2f(k2[3] * d);
            a45.x += c1.z * __builtin_amdgcn_exp2f(k2[4] * d);
            a45.y += c1.w * __builtin_amdgcn_exp2f(k2[5] * d);
            a67.x += c2.x * __builtin_amdgcn_exp2f(k2[6] * d);
            a67.y += c2.y * __builtin_amdgcn_exp2f(k2[7] * d);
        }
        scale = 1.0f;
    }

    // ---- write partials (stride-9 across lanes -> <=2-way bank aliasing) ----
    {
        float* red = &s_red[ncq][mi][0];
        red[0] = a01.x * scale;
        red[1] = a01.y * scale;
        red[2] = a23.x * scale;
        red[3] = a23.y * scale;
        red[4] = a45.x * scale;
        red[5] = a45.y * scale;
        red[6] = a67.x * scale;
        red[7] = a67.y * scale;
    }
    __syncthreads();

    // ---- reduce over 16 n-chunks: thread u<256 owns (mi=u/8, c=u%8) ----
    if (t < TM * Cc) {
        const int rmi = t >> 3;
        const int rc  = t & 7;
        float tot = 0.0f;
        #pragma unroll
        for (int k = 0; k < NCH; k++) tot += s_red[k][rmi][rc];
        s_tot[rmi][rc] = tot;
    }
    __syncthreads();
    if (t < TM * Cc) {
        const int rmi = t >> 3;
        const int rc  = t & 7;
        const float tot  = s_tot[rmi][rc];
        const float dens = s_tot[rmi][0];
        s_f[rmi][rc] = (rc == 0) ? tot : tot / (dens + 1e-8f);
    }
    __syncthreads();

    // ---- epilogue: (TM x C) @ (C x COUT) + bias, coalesced stores ----
    const long long obase = (long long)(b * Mc + m0) * COUTc;
    #pragma unroll
    for (int r = 0; r < (TM * COUTc) / THREADS; r++) {   // 4 iters
        const int flat = r * THREADS + t;
        const int o    = flat % COUTc;   // = lane -> coalesced, conflict-free
        const int rmi  = flat / COUTc;   // wave-uniform -> LDS broadcast
        float v = s_bias[o];
        #pragma unroll
        for (int c = 0; c < Cc; c++) v += s_f[rmi][c] * s_Wt[c][o];
        out[obase + flat] = v;
    }
}

extern "C" void kernel_launch(void* const* d_in, const int* in_sizes, int n_in,
                              void* d_out, int out_size, void* d_ws, size_t ws_size,
                              hipStream_t stream) {
    const float* context_in  = (const float*)d_in[0];
    const float* context_out = (const float*)d_in[1];
    const float* target_in   = (const float*)d_in[2];
    const float* sigma       = (const float*)d_in[3];
    const float* W           = (const float*)d_in[4];
    const float* bias        = (const float*)d_in[5];
    float* out = (float*)d_out;

    const int grid = Bc * (Mc / TM);  // 512 blocks x 512 threads
    convdeepset_kernel<<<grid, THREADS, 0, stream>>>(
        context_in, context_out, target_in, sigma, W, bias, out);
}

// Round 2
// 69.770 us; speedup vs baseline: 1.0112x; 1.0112x over previous
//
#include <hip/hip_runtime.h>

// ConvDeepSet: B=16, N=512, M=1024, CIN=7 (C=8 with ones-channel), COUT=64.
// out[b,m,o] = sum_c f(b,m,c) * W[o,c] + bias[o]
//   f[...,0]   = density  = sum_n exp(k_0 * d)
//   f[...,c>0] = (sum_n ctx[n,c] * exp(k_c * d)) / (density + 1e-8)
//   d = (context_in[b,n] - target_in[b,m])^2 ; k_c = -0.5 * exp(-2*sigma_c)
//
// LDS record per n: [ci, x1..x7]  (ci sits in the ones-channel slot; density
// just accumulates w directly, so the "1.0" is never multiplied).
//
// NOTE (session finding): this kernel's intrinsic cost is ~2-5 us; the bench
// window (~69 us) is dominated by the harness's 268 MB poison fill (40.5 us
// @ 83% HBM peak) plus fixed graph overhead. VALU-halving experiments (round
// 1) were neutral, confirming the kernel is not the window's bottleneck.

namespace {
constexpr int Bc    = 16;
constexpr int Nc    = 512;
constexpr int Mc    = 1024;
constexpr int CINc  = 7;
constexpr int Cc    = 8;      // 1 + CIN
constexpr int CP    = 9;      // padded channel stride for the reduce buffer
constexpr int COUTc = 64;
constexpr int TM    = 32;     // m-values per block
constexpr int NCH   = 16;     // n-chunks per block
constexpr int NPC   = Nc / NCH;       // 32 n per chunk
constexpr int THREADS = TM * NCH;     // 512 -> 8 waves/block, 2 blocks/CU, 4 waves/SIMD
constexpr float LOG2E = 1.4426950408889634f;
}

__global__ __launch_bounds__(THREADS) void convdeepset_kernel(
    const float* __restrict__ context_in,   // (B,N,1)
    const float* __restrict__ context_out,  // (B,N,CIN)
    const float* __restrict__ target_in,    // (B,M,1)
    const float* __restrict__ sigma,        // (C,)
    const float* __restrict__ W,            // (COUT,C)
    const float* __restrict__ bias,         // (COUT,)
    float* __restrict__ out)                // (B,M,COUT)
{
    __shared__ float s_ctx[Nc * Cc];           // [n][0]=ci, [n][1+c]=context_out
    __shared__ float s_red[NCH][TM][CP];       // partial sums (padded stride 9)
    __shared__ float s_tot[TM][Cc];
    __shared__ float s_f[TM][Cc];
    __shared__ float s_Wt[Cc][COUTc];
    __shared__ float s_bias[COUTc];
    __shared__ float s_k2[Cc];                 // k_c * log2(e)

    const int t   = threadIdx.x;
    const int blk = blockIdx.x;
    const int b   = blk / (Mc / TM);
    const int m0  = (blk % (Mc / TM)) * TM;

    // ---- stage constants ----
    if (t < COUTc) s_bias[t] = bias[t];
    if (t < Cc) {
        float s = sigma[t];
        float inv_sc2 = __builtin_amdgcn_exp2f(-2.0f * s * LOG2E);  // exp(-2*sigma)
        s_k2[t] = -0.5f * inv_sc2 * LOG2E;
    }
    if (t < COUTc * Cc) {               // 512 threads == 512 elements of W
        int o = t / Cc, c = t % Cc;
        s_Wt[c][o] = W[t];
    }
    // ---- stage per-batch context ----
    {
        const int n = t;                // THREADS == Nc
        s_ctx[n * Cc] = context_in[b * Nc + n];
    }
    #pragma unroll
    for (int r = 0; r < (Nc * CINc) / THREADS; r++) {   // 7 iters, exact
        int e = r * THREADS + t;
        int n = e / CINc, c = e % CINc;
        s_ctx[n * Cc + 1 + c] = context_out[b * Nc * CINc + e];
    }
    __syncthreads();

    const int mi  = t % TM;   // m within tile
    const int ncq = t / TM;   // n-chunk
    const float ti = target_in[b * Mc + m0 + mi];

    float k2[Cc];
    #pragma unroll
    for (int c = 0; c < Cc; c++) k2[c] = s_k2[c];
    bool uniform = true;
    #pragma unroll
    for (int c = 1; c < Cc; c++) uniform = uniform && (k2[c] == k2[0]);

    float acc[Cc];
    #pragma unroll
    for (int c = 0; c < Cc; c++) acc[c] = 0.0f;

    const int nbase = ncq * NPC;
    if (uniform) {
        // All channel length-scales identical (actual bench data): ONE exp per pair.
        const float k0 = k2[0];
        #pragma unroll 8
        for (int j = 0; j < NPC; j++) {
            const float4* p = (const float4*)&s_ctx[(nbase + j) * Cc];
            const float4 c0 = p[0], c1 = p[1];      // c0.x = ci
            const float diff = c0.x - ti;
            const float w = __builtin_amdgcn_exp2f((k0 * diff) * diff);
            acc[0] += w;
            acc[1] += c0.y * w; acc[2] += c0.z * w; acc[3] += c0.w * w;
            acc[4] += c1.x * w; acc[5] += c1.y * w; acc[6] += c1.z * w; acc[7] += c1.w * w;
        }
    } else {
        #pragma unroll 4
        for (int j = 0; j < NPC; j++) {
            const float4* p = (const float4*)&s_ctx[(nbase + j) * Cc];
            const float4 c0 = p[0], c1 = p[1];
            const float diff = c0.x - ti;
            const float d = diff * diff;
            acc[0] += __builtin_amdgcn_exp2f(k2[0] * d);
            acc[1] += c0.y * __builtin_amdgcn_exp2f(k2[1] * d);
            acc[2] += c0.z * __builtin_amdgcn_exp2f(k2[2] * d);
            acc[3] += c0.w * __builtin_amdgcn_exp2f(k2[3] * d);
            acc[4] += c1.x * __builtin_amdgcn_exp2f(k2[4] * d);
            acc[5] += c1.y * __builtin_amdgcn_exp2f(k2[5] * d);
            acc[6] += c1.z * __builtin_amdgcn_exp2f(k2[6] * d);
            acc[7] += c1.w * __builtin_amdgcn_exp2f(k2[7] * d);
        }
    }

    // ---- write partials (stride-9 across lanes -> all 32 banks, <=2-way) ----
    #pragma unroll
    for (int c = 0; c < Cc; c++) s_red[ncq][mi][c] = acc[c];
    __syncthreads();

    // ---- reduce over 16 n-chunks: thread u<256 owns (mi=u/8, c=u%8) ----
    if (t < TM * Cc) {
        const int rmi = t >> 3;
        const int rc  = t & 7;
        float tot = 0.0f;
        #pragma unroll
        for (int k = 0; k < NCH; k++) tot += s_red[k][rmi][rc];
        s_tot[rmi][rc] = tot;
    }
    __syncthreads();
    if (t < TM * Cc) {
        const int rmi = t >> 3;
        const int rc  = t & 7;
        const float tot  = s_tot[rmi][rc];
        const float dens = s_tot[rmi][0];
        s_f[rmi][rc] = (rc == 0) ? tot : tot / (dens + 1e-8f);
    }
    __syncthreads();

    // ---- epilogue: (TM x C) @ (C x COUT) + bias, coalesced stores ----
    const long long obase = (long long)(b * Mc + m0) * COUTc;
    #pragma unroll
    for (int r = 0; r < (TM * COUTc) / THREADS; r++) {   // 4 iters
        const int flat = r * THREADS + t;
        const int o    = flat % COUTc;   // = lane -> coalesced, conflict-free
        const int rmi  = flat / COUTc;   // wave-uniform -> LDS broadcast
        float v = s_bias[o];
        #pragma unroll
        for (int c = 0; c < Cc; c++) v += s_f[rmi][c] * s_Wt[c][o];
        out[obase + flat] = v;
    }
}

extern "C" void kernel_launch(void* const* d_in, const int* in_sizes, int n_in,
                              void* d_out, int out_size, void* d_ws, size_t ws_size,
                              hipStream_t stream) {
    const float* context_in  = (const float*)d_in[0];
    const float* context_out = (const float*)d_in[1];
    const float* target_in   = (const float*)d_in[2];
    const float* sigma       = (const float*)d_in[3];
    const float* W           = (const float*)d_in[4];
    const float* bias        = (const float*)d_in[5];
    float* out = (float*)d_out;

    const int grid = Bc * (Mc / TM);  // 512 blocks x 512 threads
    convdeepset_kernel<<<grid, THREADS, 0, stream>>>(
        context_in, context_out, target_in, sigma, W, bias, out);
}